// Round 5
// baseline (2475.744 us; speedup 1.0000x reference)
//
#include <hip/hip_runtime.h>
#include <hip/hip_bf16.h>
#include <stdint.h>

// BitLinear: out = x @ (sign(W)*(|W|>0.7*mean|W|)*scale)^T
// M=16384 (8*2048), K=4096, N=16384. All f32 in/out.
// Round 5: m201-style per-phase interleave on the 4-buffer BK=32 pipeline.
// Per K-tile: 2 phases x {ds_read frags; stage 2 gload_lds; barrier; lgkmcnt(0);
// sched_barrier; setprio(1); 16 MFMA; setprio(0); barrier}. Counted vmcnt(8)
// once per tile (tail 4->0) — never drained to 0 in steady state. Stage of
// tile t+3 split A-half (phase A) / B-half (phase B). T2 swizzle unchanged.
// Prep kernels byte-identical to rounds 1-4.

typedef __attribute__((ext_vector_type(8))) __bf16 bf16x8;
typedef __attribute__((ext_vector_type(4))) float f32x4;
typedef __attribute__((ext_vector_type(8))) unsigned short u16x8;

#define M_ROWS 16384
#define K_DIM  4096
#define N_DIM  16384

#define RED_BLOCKS 2048

// ---------- kernel 1a: per-block partial sums of |W| (deterministic) ----------
__global__ void absum_part_kernel(const float4* __restrict__ W4,
                                  double* __restrict__ part, long long n4) {
  double s = 0.0;
  const long long stride = (long long)gridDim.x * blockDim.x;
  for (long long i = (long long)blockIdx.x * blockDim.x + threadIdx.x; i < n4; i += stride) {
    float4 v = W4[i];
    s += (double)fabsf(v.x);
    s += (double)fabsf(v.y);
    s += (double)fabsf(v.z);
    s += (double)fabsf(v.w);
  }
  for (int o = 32; o > 0; o >>= 1) s += __shfl_down(s, o, 64);
  __shared__ double p[4];
  if ((threadIdx.x & 63) == 0) p[threadIdx.x >> 6] = s;
  __syncthreads();
  if (threadIdx.x == 0) part[blockIdx.x] = p[0] + p[1] + p[2] + p[3];
}

// ---------- kernel 1b: reduce partials -> total sum ----------
__global__ void reduce_sum_kernel(const double* __restrict__ part,
                                  double* __restrict__ sum, int n) {
  double s = 0.0;
  for (int i = threadIdx.x; i < n; i += blockDim.x) s += part[i];
  for (int o = 32; o > 0; o >>= 1) s += __shfl_down(s, o, 64);
  __shared__ double p[4];
  if ((threadIdx.x & 63) == 0) p[threadIdx.x >> 6] = s;
  __syncthreads();
  if (threadIdx.x == 0) *sum = p[0] + p[1] + p[2] + p[3];
}

// ---------- kernel 2: ternary-quantize W -> bf16 bit patterns ----------
__device__ __forceinline__ unsigned short tern_bf16(float w, float thr) {
  return (fabsf(w) > thr) ? ((w > 0.0f) ? (unsigned short)0x3F80u
                                        : (unsigned short)0xBF80u)
                          : (unsigned short)0u;
}

__global__ void quant_w_kernel(const float4* __restrict__ W4,
                               unsigned short* __restrict__ Wq,
                               const double* __restrict__ sum_ptr, long long n8) {
  const double mean = *sum_ptr / (double)((long long)N_DIM * K_DIM);
  const float thr = (float)(0.7 * mean);
  const long long stride = (long long)gridDim.x * blockDim.x;
  for (long long i = (long long)blockIdx.x * blockDim.x + threadIdx.x; i < n8; i += stride) {
    float4 a = W4[2 * i];
    float4 b = W4[2 * i + 1];
    u16x8 q;
    q[0] = tern_bf16(a.x, thr); q[1] = tern_bf16(a.y, thr);
    q[2] = tern_bf16(a.z, thr); q[3] = tern_bf16(a.w, thr);
    q[4] = tern_bf16(b.x, thr); q[5] = tern_bf16(b.y, thr);
    q[6] = tern_bf16(b.z, thr); q[7] = tern_bf16(b.w, thr);
    *(u16x8*)(Wq + i * 8) = q;
  }
}

// ---------- kernel 3: x f32 -> bf16 (RNE) ----------
__device__ __forceinline__ unsigned short f32_to_bf16_rne(float f) {
  unsigned int u = __float_as_uint(f);
  u += 0x7FFFu + ((u >> 16) & 1u);
  return (unsigned short)(u >> 16);
}

__global__ void cvt_x_kernel(const float4* __restrict__ X4,
                             unsigned short* __restrict__ Xb, long long n8) {
  const long long stride = (long long)gridDim.x * blockDim.x;
  for (long long i = (long long)blockIdx.x * blockDim.x + threadIdx.x; i < n8; i += stride) {
    float4 a = X4[2 * i];
    float4 b = X4[2 * i + 1];
    u16x8 q;
    q[0] = f32_to_bf16_rne(a.x); q[1] = f32_to_bf16_rne(a.y);
    q[2] = f32_to_bf16_rne(a.z); q[3] = f32_to_bf16_rne(a.w);
    q[4] = f32_to_bf16_rne(b.x); q[5] = f32_to_bf16_rne(b.y);
    q[6] = f32_to_bf16_rne(b.z); q[7] = f32_to_bf16_rne(b.w);
    *(u16x8*)(Xb + i * 8) = q;
  }
}

// ---------- kernel 4: bf16 GEMM, 256x256, BK=32, 2-phase/tile interleave ----------
#define BM 256
#define BN 256
#define BK 32
#define NT (K_DIM / BK)   // 128

__global__ __launch_bounds__(512, 2) void gemm_bt_kernel(
    const unsigned short* __restrict__ A,   // [M][K] bf16 bits
    const unsigned short* __restrict__ B,   // [N][K] bf16 bits (ternary)
    float* __restrict__ C,                  // [M][N] f32
    const float* __restrict__ scale_ptr) {
  constexpr int K = K_DIM, N = N_DIM;
  // 4 rotating buffers x {A,B} x 256 rows x 32 shorts = 128 KiB
  __shared__ __align__(16) unsigned short lds[4][2][BM][BK];

  const int tid = threadIdx.x;
  const int wave = tid >> 6;      // 0..7
  const int lane = tid & 63;

  // XCD-aware bijective swizzle (nwg = 4096, %8 == 0)
  const int nbm = M_ROWS / BM;    // 64
  const int nwg = nbm * (N / BN); // 4096
  const int wg = (blockIdx.x & 7) * (nwg >> 3) + (blockIdx.x >> 3);
  const int bm = wg % nbm;        // consecutive wg share bn -> B panel L2 reuse
  const int bn = wg / nbm;

  const int wr = wave >> 2;       // 0..1  (128 rows each)
  const int wc = wave & 3;        // 0..3  (64 cols each)

  const unsigned short* Ag = A + (size_t)(bm * BM) * K;
  const unsigned short* Bg = B + (size_t)(bn * BN) * K;

  // staging: chunk = 16 rows x 64B; LDS dest linear; bank swizzle applied
  // inverse at the global source (rule 21), same constants as rounds 3-4.
  const int strow = lane >> 2;                               // row in chunk 0..15
  const int scol = ((((lane & 3) - (lane >> 3)) & 3) << 3);  // src col in shorts

  // fragment read: row = base16 + (lane&15); slot' = (lane>>4 + (row>>1)) & 3
  const int frow = lane & 15;
  const int fsw = ((((lane >> 4) + ((lane & 15) >> 1)) & 3) << 3);  // shorts

#define STAGE_A(u)                                                                   \
  {                                                                                  \
    const int kk0_ = (u) * BK;                                                       \
    unsigned short* Ab_ = &lds[(u) & 3][0][0][0];                                    \
    _Pragma("unroll")                                                                \
    for (int i_ = 0; i_ < 2; ++i_) {                                                 \
      const int ch_ = wave * 2 + i_;                                                 \
      const int row_ = ch_ * 16 + strow;                                             \
      __builtin_amdgcn_global_load_lds(                                              \
          (__attribute__((address_space(1))) void*)(Ag + (size_t)row_ * K + kk0_ + scol), \
          (__attribute__((address_space(3))) void*)(Ab_ + ch_ * 16 * BK), 16, 0, 0); \
    }                                                                                \
  }

#define STAGE_B(u)                                                                   \
  {                                                                                  \
    const int kk0_ = (u) * BK;                                                       \
    unsigned short* Bb_ = &lds[(u) & 3][1][0][0];                                    \
    _Pragma("unroll")                                                                \
    for (int i_ = 0; i_ < 2; ++i_) {                                                 \
      const int ch_ = wave * 2 + i_;                                                 \
      const int row_ = ch_ * 16 + strow;                                             \
      __builtin_amdgcn_global_load_lds(                                              \
          (__attribute__((address_space(1))) void*)(Bg + (size_t)row_ * K + kk0_ + scol), \
          (__attribute__((address_space(3))) void*)(Bb_ + ch_ * 16 * BK), 16, 0, 0); \
    }                                                                                \
  }

  f32x4 acc[8][4] = {};

  // ---------- prologue: stage tiles 0,1,2 (12 loads/wave in flight) ----------
  STAGE_A(0); STAGE_B(0);
  STAGE_A(1); STAGE_B(1);
  STAGE_A(2); STAGE_B(2);
  asm volatile("s_waitcnt vmcnt(8)" ::: "memory");  // tile 0 landed; 1,2 in flight
  __builtin_amdgcn_s_barrier();
  __builtin_amdgcn_sched_barrier(0);

#pragma unroll 4
  for (int t = 0; t < NT; ++t) {
    const unsigned short* As_ = &lds[t & 3][0][0][0];
    const unsigned short* Bs_ = &lds[t & 3][1][0][0];
    bf16x8 af[4], bf[4], ag[4];

    // ================= phase A: m=0..3 =================
#pragma unroll
    for (int n = 0; n < 4; ++n)
      bf[n] = *(const bf16x8*)(Bs_ + (wc * 64 + n * 16 + frow) * BK + fsw);
#pragma unroll
    for (int m = 0; m < 4; ++m)
      af[m] = *(const bf16x8*)(As_ + (wr * 128 + m * 16 + frow) * BK + fsw);
    if (t + 3 < NT) STAGE_A(t + 3);
    __builtin_amdgcn_s_barrier();
    asm volatile("s_waitcnt lgkmcnt(0)" ::: "memory");
    __builtin_amdgcn_sched_barrier(0);
    __builtin_amdgcn_s_setprio(1);
#pragma unroll
    for (int m = 0; m < 4; ++m)
#pragma unroll
      for (int n = 0; n < 4; ++n)
        acc[m][n] = __builtin_amdgcn_mfma_f32_16x16x32_bf16(af[m], bf[n], acc[m][n], 0, 0, 0);
    __builtin_amdgcn_s_setprio(0);
    __builtin_amdgcn_s_barrier();

    // ================= phase B: m=4..7 =================
#pragma unroll
    for (int m = 0; m < 4; ++m)
      ag[m] = *(const bf16x8*)(As_ + (wr * 128 + (4 + m) * 16 + frow) * BK + fsw);
    if (t + 3 < NT) STAGE_B(t + 3);
    __builtin_amdgcn_s_barrier();
    asm volatile("s_waitcnt lgkmcnt(0)" ::: "memory");
    __builtin_amdgcn_sched_barrier(0);
    __builtin_amdgcn_s_setprio(1);
#pragma unroll
    for (int m = 0; m < 4; ++m)
#pragma unroll
      for (int n = 0; n < 4; ++n)
        acc[4 + m][n] = __builtin_amdgcn_mfma_f32_16x16x32_bf16(ag[m], bf[n], acc[4 + m][n], 0, 0, 0);
    __builtin_amdgcn_s_setprio(0);
    __builtin_amdgcn_sched_barrier(0);
    // counted wait for tile t+1: stages t+2, t+3 stay in flight (8 loads).
    if (t < NT - 3) {
      asm volatile("s_waitcnt vmcnt(8)" ::: "memory");
    } else if (t == NT - 3) {
      asm volatile("s_waitcnt vmcnt(4)" ::: "memory");
    } else if (t == NT - 2) {
      asm volatile("s_waitcnt vmcnt(0)" ::: "memory");
    }
    if (t + 1 < NT) __builtin_amdgcn_s_barrier();
    __builtin_amdgcn_sched_barrier(0);
  }
#undef STAGE_A
#undef STAGE_B

  // ---------------- epilogue ----------------
  const float scale = *scale_ptr;
  const int crow0 = bm * BM + wr * 128;
  const int ccol0 = bn * BN + wc * 64;
#pragma unroll
  for (int m = 0; m < 8; ++m)
#pragma unroll
    for (int n = 0; n < 4; ++n)
#pragma unroll
      for (int j = 0; j < 4; ++j) {
        // C/D layout (m89-verified): col = lane&15, row = (lane>>4)*4 + j
        const int row = crow0 + m * 16 + ((lane >> 4) << 2) + j;
        const int col = ccol0 + n * 16 + (lane & 15);
        C[(size_t)row * N + col] = acc[m][n][j] * scale;
      }
}

extern "C" void kernel_launch(void* const* d_in, const int* in_sizes, int n_in,
                              void* d_out, int out_size, void* d_ws, size_t ws_size,
                              hipStream_t stream) {
  (void)in_sizes; (void)n_in; (void)out_size; (void)ws_size;
  const float* x = (const float*)d_in[0];
  const float* w = (const float*)d_in[1];
  const float* scale = (const float*)d_in[2];
  float* out = (float*)d_out;

  char* ws = (char*)d_ws;
  double* part = (double*)ws;
  double* sum = (double*)(ws + 16384);
  unsigned short* Wq = (unsigned short*)(ws + 32768);
  unsigned short* Xb = (unsigned short*)(ws + 32768 + (size_t)N_DIM * K_DIM * 2);

  const long long nW = (long long)N_DIM * K_DIM;   // 67108864
  const long long nX = (long long)M_ROWS * K_DIM;  // 67108864

  absum_part_kernel<<<RED_BLOCKS, 256, 0, stream>>>((const float4*)w, part, nW / 4);
  reduce_sum_kernel<<<1, 256, 0, stream>>>(part, sum, RED_BLOCKS);
  quant_w_kernel<<<2048, 256, 0, stream>>>((const float4*)w, Wq, sum, nW / 8);
  cvt_x_kernel<<<2048, 256, 0, stream>>>((const float4*)x, Xb, nX / 8);

  const int nblocks = (M_ROWS / BM) * (N_DIM / BN);  // 4096
  gemm_bt_kernel<<<nblocks, 512, 0, stream>>>(Xb, Wq, out, scale);
}

// Round 6
// 2178.666 us; speedup vs baseline: 1.1364x; 1.1364x over previous
//
#include <hip/hip_runtime.h>
#include <hip/hip_bf16.h>
#include <stdint.h>

// BitLinear: out = x @ (sign(W)*(|W|>0.7*mean|W|)*scale)^T
// M=16384 (8*2048), K=4096, N=16384. All f32 in/out.
// Round 6: AITER-style instruction-level interleave. Per K-tile, ONE barrier;
// MFMA cluster first (operands from regs, loaded last tile), with the 12
// ds_read_b128 for tile t+1 threaded between 4-MFMA groups (2 reads/group,
// sched_barrier-pinned). lgkm wait for those reads happens NEXT iter, after
// the barrier — reads retire under the MFMA grinding. Counted vmcnt(8),
// 4 rotating LDS buffers, stage t+3 ahead, T2 swizzle — as rounds 3-4.
// Prep kernels byte-identical to rounds 1-5.

typedef __attribute__((ext_vector_type(8))) __bf16 bf16x8;
typedef __attribute__((ext_vector_type(4))) float f32x4;
typedef __attribute__((ext_vector_type(8))) unsigned short u16x8;

#define M_ROWS 16384
#define K_DIM  4096
#define N_DIM  16384

#define RED_BLOCKS 2048

// ---------- kernel 1a: per-block partial sums of |W| (deterministic) ----------
__global__ void absum_part_kernel(const float4* __restrict__ W4,
                                  double* __restrict__ part, long long n4) {
  double s = 0.0;
  const long long stride = (long long)gridDim.x * blockDim.x;
  for (long long i = (long long)blockIdx.x * blockDim.x + threadIdx.x; i < n4; i += stride) {
    float4 v = W4[i];
    s += (double)fabsf(v.x);
    s += (double)fabsf(v.y);
    s += (double)fabsf(v.z);
    s += (double)fabsf(v.w);
  }
  for (int o = 32; o > 0; o >>= 1) s += __shfl_down(s, o, 64);
  __shared__ double p[4];
  if ((threadIdx.x & 63) == 0) p[threadIdx.x >> 6] = s;
  __syncthreads();
  if (threadIdx.x == 0) part[blockIdx.x] = p[0] + p[1] + p[2] + p[3];
}

// ---------- kernel 1b: reduce partials -> total sum ----------
__global__ void reduce_sum_kernel(const double* __restrict__ part,
                                  double* __restrict__ sum, int n) {
  double s = 0.0;
  for (int i = threadIdx.x; i < n; i += blockDim.x) s += part[i];
  for (int o = 32; o > 0; o >>= 1) s += __shfl_down(s, o, 64);
  __shared__ double p[4];
  if ((threadIdx.x & 63) == 0) p[threadIdx.x >> 6] = s;
  __syncthreads();
  if (threadIdx.x == 0) *sum = p[0] + p[1] + p[2] + p[3];
}

// ---------- kernel 2: ternary-quantize W -> bf16 bit patterns ----------
__device__ __forceinline__ unsigned short tern_bf16(float w, float thr) {
  return (fabsf(w) > thr) ? ((w > 0.0f) ? (unsigned short)0x3F80u
                                        : (unsigned short)0xBF80u)
                          : (unsigned short)0u;
}

__global__ void quant_w_kernel(const float4* __restrict__ W4,
                               unsigned short* __restrict__ Wq,
                               const double* __restrict__ sum_ptr, long long n8) {
  const double mean = *sum_ptr / (double)((long long)N_DIM * K_DIM);
  const float thr = (float)(0.7 * mean);
  const long long stride = (long long)gridDim.x * blockDim.x;
  for (long long i = (long long)blockIdx.x * blockDim.x + threadIdx.x; i < n8; i += stride) {
    float4 a = W4[2 * i];
    float4 b = W4[2 * i + 1];
    u16x8 q;
    q[0] = tern_bf16(a.x, thr); q[1] = tern_bf16(a.y, thr);
    q[2] = tern_bf16(a.z, thr); q[3] = tern_bf16(a.w, thr);
    q[4] = tern_bf16(b.x, thr); q[5] = tern_bf16(b.y, thr);
    q[6] = tern_bf16(b.z, thr); q[7] = tern_bf16(b.w, thr);
    *(u16x8*)(Wq + i * 8) = q;
  }
}

// ---------- kernel 3: x f32 -> bf16 (RNE) ----------
__device__ __forceinline__ unsigned short f32_to_bf16_rne(float f) {
  unsigned int u = __float_as_uint(f);
  u += 0x7FFFu + ((u >> 16) & 1u);
  return (unsigned short)(u >> 16);
}

__global__ void cvt_x_kernel(const float4* __restrict__ X4,
                             unsigned short* __restrict__ Xb, long long n8) {
  const long long stride = (long long)gridDim.x * blockDim.x;
  for (long long i = (long long)blockIdx.x * blockDim.x + threadIdx.x; i < n8; i += stride) {
    float4 a = X4[2 * i];
    float4 b = X4[2 * i + 1];
    u16x8 q;
    q[0] = f32_to_bf16_rne(a.x); q[1] = f32_to_bf16_rne(a.y);
    q[2] = f32_to_bf16_rne(a.z); q[3] = f32_to_bf16_rne(a.w);
    q[4] = f32_to_bf16_rne(b.x); q[5] = f32_to_bf16_rne(b.y);
    q[6] = f32_to_bf16_rne(b.z); q[7] = f32_to_bf16_rne(b.w);
    *(u16x8*)(Xb + i * 8) = q;
  }
}

// ---------- kernel 4: bf16 GEMM, 256x256, BK=32, MFMA<->ds_read interleave ----------
#define BM 256
#define BN 256
#define BK 32
#define NT (K_DIM / BK)   // 128

__global__ __launch_bounds__(512, 2) void gemm_bt_kernel(
    const unsigned short* __restrict__ A,   // [M][K] bf16 bits
    const unsigned short* __restrict__ B,   // [N][K] bf16 bits (ternary)
    float* __restrict__ C,                  // [M][N] f32
    const float* __restrict__ scale_ptr) {
  constexpr int K = K_DIM, N = N_DIM;
  // 4 rotating buffers x {A,B} x 256 rows x 32 shorts = 128 KiB
  __shared__ __align__(16) unsigned short lds[4][2][BM][BK];

  const int tid = threadIdx.x;
  const int wave = tid >> 6;      // 0..7
  const int lane = tid & 63;

  // XCD-aware bijective swizzle (nwg = 4096, %8 == 0)
  const int nbm = M_ROWS / BM;    // 64
  const int nwg = nbm * (N / BN); // 4096
  const int wg = (blockIdx.x & 7) * (nwg >> 3) + (blockIdx.x >> 3);
  const int bm = wg % nbm;        // consecutive wg share bn -> B panel L2 reuse
  const int bn = wg / nbm;

  const int wr = wave >> 2;       // 0..1  (128 rows each)
  const int wc = wave & 3;        // 0..3  (64 cols each)

  const unsigned short* Ag = A + (size_t)(bm * BM) * K;
  const unsigned short* Bg = B + (size_t)(bn * BN) * K;

  // staging: chunk = 16 rows x 64B; LDS dest linear; bank swizzle applied
  // inverse at the global source (rule 21), same constants as rounds 3-5.
  const int strow = lane >> 2;                               // row in chunk 0..15
  const int scol = ((((lane & 3) - (lane >> 3)) & 3) << 3);  // src col in shorts

  // fragment read: row = base16 + (lane&15); slot' = (lane>>4 + (row>>1)) & 3
  const int frow = lane & 15;
  const int fsw = ((((lane >> 4) + ((lane & 15) >> 1)) & 3) << 3);  // shorts

#define STAGE(u)                                                                     \
  {                                                                                  \
    const int kk0_ = (u) * BK;                                                       \
    unsigned short* Ab_ = &lds[(u) & 3][0][0][0];                                    \
    unsigned short* Bb_ = &lds[(u) & 3][1][0][0];                                    \
    _Pragma("unroll")                                                                \
    for (int i_ = 0; i_ < 2; ++i_) {                                                 \
      const int ch_ = wave * 2 + i_;                                                 \
      const int row_ = ch_ * 16 + strow;                                             \
      __builtin_amdgcn_global_load_lds(                                              \
          (__attribute__((address_space(1))) void*)(Ag + (size_t)row_ * K + kk0_ + scol), \
          (__attribute__((address_space(3))) void*)(Ab_ + ch_ * 16 * BK), 16, 0, 0); \
      __builtin_amdgcn_global_load_lds(                                              \
          (__attribute__((address_space(1))) void*)(Bg + (size_t)row_ * K + kk0_ + scol), \
          (__attribute__((address_space(3))) void*)(Bb_ + ch_ * 16 * BK), 16, 0, 0); \
    }                                                                                \
  }

#define RD_B(P, n_) (*(const bf16x8*)((P) + (wc * 64 + (n_) * 16 + frow) * BK + fsw))
#define RD_A(P, m_) (*(const bf16x8*)((P) + (wr * 128 + (m_) * 16 + frow) * BK + fsw))

#define MF4(m_, CA, CB)                                                              \
  {                                                                                  \
    _Pragma("unroll")                                                                \
    for (int n_ = 0; n_ < 4; ++n_)                                                   \
      acc[m_][n_] = __builtin_amdgcn_mfma_f32_16x16x32_bf16(CA[m_], CB[n_],          \
                                                            acc[m_][n_], 0, 0, 0);   \
  }

  // iter: STAGE(t+3) -> counted vmcnt -> barrier -> lgkm(0) [frags(t) ready] ->
  // MFMA cluster with frags(t+1) reads threaded between groups (2 per group).
#define ITER(T, CA, CB, NA, NB, RD)                                                  \
  {                                                                                  \
    if ((T) + 3 < NT) STAGE((T) + 3);                                                \
    __builtin_amdgcn_sched_barrier(0);                                               \
    if ((T) < NT - 3) {                                                              \
      asm volatile("s_waitcnt vmcnt(8)" ::: "memory");                               \
    } else if ((T) == NT - 3) {                                                      \
      asm volatile("s_waitcnt vmcnt(4)" ::: "memory");                               \
    } else if ((T) == NT - 2) {                                                      \
      asm volatile("s_waitcnt vmcnt(0)" ::: "memory");                               \
    }                                                                                \
    __builtin_amdgcn_s_barrier();                                                    \
    asm volatile("s_waitcnt lgkmcnt(0)" ::: "memory");                               \
    __builtin_amdgcn_sched_barrier(0);                                               \
    const unsigned short* NAp_ = &lds[((T) + 1) & 3][0][0][0];                       \
    const unsigned short* NBp_ = &lds[((T) + 1) & 3][1][0][0];                       \
    __builtin_amdgcn_s_setprio(1);                                                   \
    MF4(0, CA, CB);                                                                  \
    __builtin_amdgcn_sched_barrier(0);                                               \
    if (RD) { NB[0] = RD_B(NBp_, 0); NB[1] = RD_B(NBp_, 1); }                        \
    __builtin_amdgcn_sched_barrier(0);                                               \
    MF4(1, CA, CB);                                                                  \
    __builtin_amdgcn_sched_barrier(0);                                               \
    if (RD) { NB[2] = RD_B(NBp_, 2); NB[3] = RD_B(NBp_, 3); }                        \
    __builtin_amdgcn_sched_barrier(0);                                               \
    MF4(2, CA, CB);                                                                  \
    __builtin_amdgcn_sched_barrier(0);                                               \
    if (RD) { NA[0] = RD_A(NAp_, 0); NA[1] = RD_A(NAp_, 1); }                        \
    __builtin_amdgcn_sched_barrier(0);                                               \
    MF4(3, CA, CB);                                                                  \
    __builtin_amdgcn_sched_barrier(0);                                               \
    if (RD) { NA[2] = RD_A(NAp_, 2); NA[3] = RD_A(NAp_, 3); }                        \
    __builtin_amdgcn_sched_barrier(0);                                               \
    MF4(4, CA, CB);                                                                  \
    __builtin_amdgcn_sched_barrier(0);                                               \
    if (RD) { NA[4] = RD_A(NAp_, 4); NA[5] = RD_A(NAp_, 5); }                        \
    __builtin_amdgcn_sched_barrier(0);                                               \
    MF4(5, CA, CB);                                                                  \
    __builtin_amdgcn_sched_barrier(0);                                               \
    if (RD) { NA[6] = RD_A(NAp_, 6); NA[7] = RD_A(NAp_, 7); }                        \
    __builtin_amdgcn_sched_barrier(0);                                               \
    MF4(6, CA, CB);                                                                  \
    MF4(7, CA, CB);                                                                  \
    __builtin_amdgcn_s_setprio(0);                                                   \
    __builtin_amdgcn_sched_barrier(0);                                               \
  }

  f32x4 acc[8][4] = {};
  bf16x8 af0[8], bf0[4], af1[8], bf1[4];

  // ---------- prologue: stage 0,1,2; read frags(0) into set0 ----------
  STAGE(0);
  STAGE(1);
  STAGE(2);
  asm volatile("s_waitcnt vmcnt(8)" ::: "memory");  // tile 0 landed; 1,2 in flight
  __builtin_amdgcn_s_barrier();
  __builtin_amdgcn_sched_barrier(0);
#pragma unroll
  for (int n = 0; n < 4; ++n) bf0[n] = RD_B(&lds[0][1][0][0], n);
#pragma unroll
  for (int m = 0; m < 8; ++m) af0[m] = RD_A(&lds[0][0][0][0], m);
  __builtin_amdgcn_sched_barrier(0);

  for (int t = 0; t < NT - 2; t += 2) {
    ITER(t, af0, bf0, af1, bf1, 1);
    ITER(t + 1, af1, bf1, af0, bf0, 1);
  }
  ITER(NT - 2, af0, bf0, af1, bf1, 1);   // t = 126 (even): current set0
  ITER(NT - 1, af1, bf1, af0, bf0, 0);   // t = 127: no further reads
#undef ITER
#undef MF4
#undef RD_A
#undef RD_B
#undef STAGE

  // ---------------- epilogue ----------------
  const float scale = *scale_ptr;
  const int crow0 = bm * BM + wr * 128;
  const int ccol0 = bn * BN + wc * 64;
#pragma unroll
  for (int m = 0; m < 8; ++m)
#pragma unroll
    for (int n = 0; n < 4; ++n)
#pragma unroll
      for (int j = 0; j < 4; ++j) {
        // C/D layout (m89-verified): col = lane&15, row = (lane>>4)*4 + j
        const int row = crow0 + m * 16 + ((lane >> 4) << 2) + j;
        const int col = ccol0 + n * 16 + (lane & 15);
        C[(size_t)row * N + col] = acc[m][n][j] * scale;
      }
}

extern "C" void kernel_launch(void* const* d_in, const int* in_sizes, int n_in,
                              void* d_out, int out_size, void* d_ws, size_t ws_size,
                              hipStream_t stream) {
  (void)in_sizes; (void)n_in; (void)out_size; (void)ws_size;
  const float* x = (const float*)d_in[0];
  const float* w = (const float*)d_in[1];
  const float* scale = (const float*)d_in[2];
  float* out = (float*)d_out;

  char* ws = (char*)d_ws;
  double* part = (double*)ws;
  double* sum = (double*)(ws + 16384);
  unsigned short* Wq = (unsigned short*)(ws + 32768);
  unsigned short* Xb = (unsigned short*)(ws + 32768 + (size_t)N_DIM * K_DIM * 2);

  const long long nW = (long long)N_DIM * K_DIM;   // 67108864
  const long long nX = (long long)M_ROWS * K_DIM;  // 67108864

  absum_part_kernel<<<RED_BLOCKS, 256, 0, stream>>>((const float4*)w, part, nW / 4);
  reduce_sum_kernel<<<1, 256, 0, stream>>>(part, sum, RED_BLOCKS);
  quant_w_kernel<<<2048, 256, 0, stream>>>((const float4*)w, Wq, sum, nW / 8);
  cvt_x_kernel<<<2048, 256, 0, stream>>>((const float4*)x, Xb, nX / 8);

  const int nblocks = (M_ROWS / BM) * (N_DIM / BN);  // 4096
  gemm_bt_kernel<<<nblocks, 512, 0, stream>>>(Xb, Wq, out, scale);
}

// Round 7
// 2073.129 us; speedup vs baseline: 1.1942x; 1.0509x over previous
//
#include <hip/hip_runtime.h>
#include <hip/hip_bf16.h>
#include <stdint.h>

// BitLinear: out = x @ (sign(W)*(|W|>0.7*mean|W|)*scale)^T
// M=16384 (8*2048), K=4096, N=16384. All f32 in/out.
// Round 7: r6 schedule (MFMA<->ds_read interleave, counted vmcnt(8), 4 LDS
// buffers, T2 swizzle) with two orthogonal changes:
//  (a) mfma_f32_32x32x16_bf16: 32768 FLOP / 8.07cyc vs 16384 / 4.85 ->
//      per-tile matrix time 1242->1033 cyc, half the MFMA instructions.
//      A/B frag: row|col = lane&31, k = (lane>>5)*8 + e. C/D: col=lane&31,
//      row=(reg&3)+8*(reg>>2)+4*(lane>>5)  [m74/m101-verified].
//  (b) 2D-clustered XCD map: XCD x owns bn in [8x,8x+8); co-resident batches
//      form 4bm x 8bn rectangles -> A slabs shared 8-way, B 4-way in L2.
// Prep kernels byte-identical to rounds 1-6.

typedef __attribute__((ext_vector_type(8))) __bf16 bf16x8;
typedef __attribute__((ext_vector_type(16))) float f32x16;
typedef __attribute__((ext_vector_type(8))) unsigned short u16x8;

#define M_ROWS 16384
#define K_DIM  4096
#define N_DIM  16384

#define RED_BLOCKS 2048

// ---------- kernel 1a: per-block partial sums of |W| (deterministic) ----------
__global__ void absum_part_kernel(const float4* __restrict__ W4,
                                  double* __restrict__ part, long long n4) {
  double s = 0.0;
  const long long stride = (long long)gridDim.x * blockDim.x;
  for (long long i = (long long)blockIdx.x * blockDim.x + threadIdx.x; i < n4; i += stride) {
    float4 v = W4[i];
    s += (double)fabsf(v.x);
    s += (double)fabsf(v.y);
    s += (double)fabsf(v.z);
    s += (double)fabsf(v.w);
  }
  for (int o = 32; o > 0; o >>= 1) s += __shfl_down(s, o, 64);
  __shared__ double p[4];
  if ((threadIdx.x & 63) == 0) p[threadIdx.x >> 6] = s;
  __syncthreads();
  if (threadIdx.x == 0) part[blockIdx.x] = p[0] + p[1] + p[2] + p[3];
}

// ---------- kernel 1b: reduce partials -> total sum ----------
__global__ void reduce_sum_kernel(const double* __restrict__ part,
                                  double* __restrict__ sum, int n) {
  double s = 0.0;
  for (int i = threadIdx.x; i < n; i += blockDim.x) s += part[i];
  for (int o = 32; o > 0; o >>= 1) s += __shfl_down(s, o, 64);
  __shared__ double p[4];
  if ((threadIdx.x & 63) == 0) p[threadIdx.x >> 6] = s;
  __syncthreads();
  if (threadIdx.x == 0) *sum = p[0] + p[1] + p[2] + p[3];
}

// ---------- kernel 2: ternary-quantize W -> bf16 bit patterns ----------
__device__ __forceinline__ unsigned short tern_bf16(float w, float thr) {
  return (fabsf(w) > thr) ? ((w > 0.0f) ? (unsigned short)0x3F80u
                                        : (unsigned short)0xBF80u)
                          : (unsigned short)0u;
}

__global__ void quant_w_kernel(const float4* __restrict__ W4,
                               unsigned short* __restrict__ Wq,
                               const double* __restrict__ sum_ptr, long long n8) {
  const double mean = *sum_ptr / (double)((long long)N_DIM * K_DIM);
  const float thr = (float)(0.7 * mean);
  const long long stride = (long long)gridDim.x * blockDim.x;
  for (long long i = (long long)blockIdx.x * blockDim.x + threadIdx.x; i < n8; i += stride) {
    float4 a = W4[2 * i];
    float4 b = W4[2 * i + 1];
    u16x8 q;
    q[0] = tern_bf16(a.x, thr); q[1] = tern_bf16(a.y, thr);
    q[2] = tern_bf16(a.z, thr); q[3] = tern_bf16(a.w, thr);
    q[4] = tern_bf16(b.x, thr); q[5] = tern_bf16(b.y, thr);
    q[6] = tern_bf16(b.z, thr); q[7] = tern_bf16(b.w, thr);
    *(u16x8*)(Wq + i * 8) = q;
  }
}

// ---------- kernel 3: x f32 -> bf16 (RNE) ----------
__device__ __forceinline__ unsigned short f32_to_bf16_rne(float f) {
  unsigned int u = __float_as_uint(f);
  u += 0x7FFFu + ((u >> 16) & 1u);
  return (unsigned short)(u >> 16);
}

__global__ void cvt_x_kernel(const float4* __restrict__ X4,
                             unsigned short* __restrict__ Xb, long long n8) {
  const long long stride = (long long)gridDim.x * blockDim.x;
  for (long long i = (long long)blockIdx.x * blockDim.x + threadIdx.x; i < n8; i += stride) {
    float4 a = X4[2 * i];
    float4 b = X4[2 * i + 1];
    u16x8 q;
    q[0] = f32_to_bf16_rne(a.x); q[1] = f32_to_bf16_rne(a.y);
    q[2] = f32_to_bf16_rne(a.z); q[3] = f32_to_bf16_rne(a.w);
    q[4] = f32_to_bf16_rne(b.x); q[5] = f32_to_bf16_rne(b.y);
    q[6] = f32_to_bf16_rne(b.z); q[7] = f32_to_bf16_rne(b.w);
    *(u16x8*)(Xb + i * 8) = q;
  }
}

// ---------- kernel 4: bf16 GEMM, 256x256, BK=32, 32x32x16 MFMA ----------
#define BM 256
#define BN 256
#define BK 32
#define NT (K_DIM / BK)   // 128

__global__ __launch_bounds__(512, 2) void gemm_bt_kernel(
    const unsigned short* __restrict__ A,   // [M][K] bf16 bits
    const unsigned short* __restrict__ B,   // [N][K] bf16 bits (ternary)
    float* __restrict__ C,                  // [M][N] f32
    const float* __restrict__ scale_ptr) {
  constexpr int K = K_DIM, N = N_DIM;
  // 4 rotating buffers x {A,B} x 256 rows x 32 shorts = 128 KiB
  __shared__ __align__(16) unsigned short lds[4][2][BM][BK];

  const int tid = threadIdx.x;
  const int wave = tid >> 6;      // 0..7
  const int lane = tid & 63;

  // 2D-clustered XCD map: XCD x owns bn-slab [8x, 8x+8); co-resident batches
  // of 32 wgs (l consecutive) form 4bm x 8bn rectangles.
  const int x = blockIdx.x & 7;   // XCD
  const int l = blockIdx.x >> 3;  // 0..511 within XCD
  const int g = l >> 5;           // round 0..15
  const int s = l & 31;           // position in 4x8 rectangle
  const int bm = g * 4 + (s & 3); // 0..63
  const int bn = x * 8 + (s >> 2);// 0..63

  const int wr = wave >> 2;       // 0..1  (128 rows each)
  const int wc = wave & 3;        // 0..3  (64 cols each)

  const unsigned short* Ag = A + (size_t)(bm * BM) * K;
  const unsigned short* Bg = B + (size_t)(bn * BN) * K;

  // staging: chunk = 16 rows x 64B; LDS dest linear; bank swizzle applied
  // inverse at the global source (rule 21): LDS[r][s'] = G[r][(s'-(r>>1))&3].
  const int strow = lane >> 2;                               // row in chunk 0..15
  const int scol = ((((lane & 3) - (lane >> 3)) & 3) << 3);  // src col in shorts

  // fragment read (32x32 frags): row = base32 + (lane&31); logical slot =
  // ks*2 + (lane>>5); read slot' = (logical + (row>>1)) & 3.
  const int frow32 = lane & 31;
  const int khalf = lane >> 5;
  const int rc0 = (((khalf + (frow32 >> 1)) & 3) << 3);      // ks=0, shorts
  const int rc1 = (((2 + khalf + (frow32 >> 1)) & 3) << 3);  // ks=1, shorts

#define STAGE(u)                                                                     \
  {                                                                                  \
    const int kk0_ = (u) * BK;                                                       \
    unsigned short* Ab_ = &lds[(u) & 3][0][0][0];                                    \
    unsigned short* Bb_ = &lds[(u) & 3][1][0][0];                                    \
    _Pragma("unroll")                                                                \
    for (int i_ = 0; i_ < 2; ++i_) {                                                 \
      const int ch_ = wave * 2 + i_;                                                 \
      const int row_ = ch_ * 16 + strow;                                             \
      __builtin_amdgcn_global_load_lds(                                              \
          (__attribute__((address_space(1))) void*)(Ag + (size_t)row_ * K + kk0_ + scol), \
          (__attribute__((address_space(3))) void*)(Ab_ + ch_ * 16 * BK), 16, 0, 0); \
      __builtin_amdgcn_global_load_lds(                                              \
          (__attribute__((address_space(1))) void*)(Bg + (size_t)row_ * K + kk0_ + scol), \
          (__attribute__((address_space(3))) void*)(Bb_ + ch_ * 16 * BK), 16, 0, 0); \
    }                                                                                \
  }

#define RD_A(P, mb, ks) \
  (*(const bf16x8*)((P) + (wr * 128 + (mb) * 32 + frow32) * BK + ((ks) ? rc1 : rc0)))
#define RD_B(P, nb, ks) \
  (*(const bf16x8*)((P) + (wc * 64 + (nb) * 32 + frow32) * BK + ((ks) ? rc1 : rc0)))

#define MF2(mb, ks, CA, CB)                                                          \
  {                                                                                  \
    acc[mb][0] = __builtin_amdgcn_mfma_f32_32x32x16_bf16(CA[mb][ks], CB[0][ks],      \
                                                         acc[mb][0], 0, 0, 0);       \
    acc[mb][1] = __builtin_amdgcn_mfma_f32_32x32x16_bf16(CA[mb][ks], CB[1][ks],      \
                                                         acc[mb][1], 0, 0, 0);       \
  }

#define SB __builtin_amdgcn_sched_barrier(0)

  // iter: STAGE(t+3) -> counted vmcnt -> barrier -> lgkm(0) [frags(t) ready] ->
  // 8 MF2 groups with frags(t+1) reads threaded between groups (2 per gap).
#define ITER(T, CA, CB, NA, NB, RD)                                                  \
  {                                                                                  \
    if ((T) + 3 < NT) STAGE((T) + 3);                                                \
    SB;                                                                              \
    if ((T) < NT - 3) {                                                              \
      asm volatile("s_waitcnt vmcnt(8)" ::: "memory");                               \
    } else if ((T) == NT - 3) {                                                      \
      asm volatile("s_waitcnt vmcnt(4)" ::: "memory");                               \
    } else if ((T) == NT - 2) {                                                      \
      asm volatile("s_waitcnt vmcnt(0)" ::: "memory");                               \
    }                                                                                \
    __builtin_amdgcn_s_barrier();                                                    \
    asm volatile("s_waitcnt lgkmcnt(0)" ::: "memory");                               \
    SB;                                                                              \
    const unsigned short* NAp_ = &lds[((T) + 1) & 3][0][0][0];                       \
    const unsigned short* NBp_ = &lds[((T) + 1) & 3][1][0][0];                       \
    __builtin_amdgcn_s_setprio(1);                                                   \
    MF2(0, 0, CA, CB);                                                               \
    SB;                                                                              \
    if (RD) { NB[0][0] = RD_B(NBp_, 0, 0); NB[1][0] = RD_B(NBp_, 1, 0); }            \
    SB;                                                                              \
    MF2(1, 0, CA, CB);                                                               \
    SB;                                                                              \
    if (RD) { NB[0][1] = RD_B(NBp_, 0, 1); NB[1][1] = RD_B(NBp_, 1, 1); }            \
    SB;                                                                              \
    MF2(2, 0, CA, CB);                                                               \
    SB;                                                                              \
    if (RD) { NA[0][0] = RD_A(NAp_, 0, 0); NA[1][0] = RD_A(NAp_, 1, 0); }            \
    SB;                                                                              \
    MF2(3, 0, CA, CB);                                                               \
    SB;                                                                              \
    if (RD) { NA[2][0] = RD_A(NAp_, 2, 0); NA[3][0] = RD_A(NAp_, 3, 0); }            \
    SB;                                                                              \
    MF2(0, 1, CA, CB);                                                               \
    SB;                                                                              \
    if (RD) { NA[0][1] = RD_A(NAp_, 0, 1); NA[1][1] = RD_A(NAp_, 1, 1); }            \
    SB;                                                                              \
    MF2(1, 1, CA, CB);                                                               \
    SB;                                                                              \
    if (RD) { NA[2][1] = RD_A(NAp_, 2, 1); NA[3][1] = RD_A(NAp_, 3, 1); }            \
    SB;                                                                              \
    MF2(2, 1, CA, CB);                                                               \
    MF2(3, 1, CA, CB);                                                               \
    __builtin_amdgcn_s_setprio(0);                                                   \
    SB;                                                                              \
  }

  f32x16 acc[4][2] = {};
  bf16x8 af0[4][2], bf0[2][2], af1[4][2], bf1[2][2];

  // ---------- prologue: stage 0,1,2; read frags(0) into set0 ----------
  STAGE(0);
  STAGE(1);
  STAGE(2);
  asm volatile("s_waitcnt vmcnt(8)" ::: "memory");  // tile 0 landed; 1,2 in flight
  __builtin_amdgcn_s_barrier();
  SB;
#pragma unroll
  for (int nb = 0; nb < 2; ++nb) {
    bf0[nb][0] = RD_B(&lds[0][1][0][0], nb, 0);
    bf0[nb][1] = RD_B(&lds[0][1][0][0], nb, 1);
  }
#pragma unroll
  for (int mb = 0; mb < 4; ++mb) {
    af0[mb][0] = RD_A(&lds[0][0][0][0], mb, 0);
    af0[mb][1] = RD_A(&lds[0][0][0][0], mb, 1);
  }
  SB;

  for (int t = 0; t < NT - 2; t += 2) {
    ITER(t, af0, bf0, af1, bf1, 1);
    ITER(t + 1, af1, bf1, af0, bf0, 1);
  }
  ITER(NT - 2, af0, bf0, af1, bf1, 1);   // t = 126 (even): current set0
  ITER(NT - 1, af1, bf1, af0, bf0, 0);   // t = 127: no further reads
#undef ITER
#undef SB
#undef MF2
#undef RD_A
#undef RD_B
#undef STAGE

  // ---------------- epilogue ----------------
  const float scale = *scale_ptr;
  const int crow0 = bm * BM + wr * 128;
  const int ccol0 = bn * BN + wc * 64;
#pragma unroll
  for (int mb = 0; mb < 4; ++mb)
#pragma unroll
    for (int nb = 0; nb < 2; ++nb)
#pragma unroll
      for (int reg = 0; reg < 16; ++reg) {
        // C/D 32x32 (m74/m101): col = lane&31, row = (reg&3)+8*(reg>>2)+4*(lane>>5)
        const int row = crow0 + mb * 32 + (reg & 3) + 8 * (reg >> 2) + 4 * khalf;
        const int col = ccol0 + nb * 32 + frow32;
        C[(size_t)row * N + col] = acc[mb][nb][reg] * scale;
      }
}

extern "C" void kernel_launch(void* const* d_in, const int* in_sizes, int n_in,
                              void* d_out, int out_size, void* d_ws, size_t ws_size,
                              hipStream_t stream) {
  (void)in_sizes; (void)n_in; (void)out_size; (void)ws_size;
  const float* x = (const float*)d_in[0];
  const float* w = (const float*)d_in[1];
  const float* scale = (const float*)d_in[2];
  float* out = (float*)d_out;

  char* ws = (char*)d_ws;
  double* part = (double*)ws;
  double* sum = (double*)(ws + 16384);
  unsigned short* Wq = (unsigned short*)(ws + 32768);
  unsigned short* Xb = (unsigned short*)(ws + 32768 + (size_t)N_DIM * K_DIM * 2);

  const long long nW = (long long)N_DIM * K_DIM;   // 67108864
  const long long nX = (long long)M_ROWS * K_DIM;  // 67108864

  absum_part_kernel<<<RED_BLOCKS, 256, 0, stream>>>((const float4*)w, part, nW / 4);
  reduce_sum_kernel<<<1, 256, 0, stream>>>(part, sum, RED_BLOCKS);
  quant_w_kernel<<<2048, 256, 0, stream>>>((const float4*)w, Wq, sum, nW / 8);
  cvt_x_kernel<<<2048, 256, 0, stream>>>((const float4*)x, Xb, nX / 8);

  const int nblocks = (M_ROWS / BM) * (N_DIM / BN);  // 4096
  gemm_bt_kernel<<<nblocks, 512, 0, stream>>>(Xb, Wq, out, scale);
}